// Round 2
// baseline (261.942 us; speedup 1.0000x reference)
//
#include <hip/hip_runtime.h>
#include <math.h>

#define NPTS 2000000
#define DIM 16
#define NCL 64
#define EPSF 1e-8f

// ws float layout:
//   [0,1024)    sums[64][16]
//   [1024,1088) counts[64]
//   [1088,2112) means[64][16]
//   [2112,2176) h2sums[64]
//   [2176]      inter_loss
//   [2177]      reg_loss
#define WS_SUMS   0
#define WS_CNT    1024
#define WS_MEANS  1088
#define WS_H2     2112
#define WS_INTER  2176
#define WS_REG    2177
#define WS_FLOATS 2178

// Pass 1: per-cluster feature sums + counts.
// 4 lanes per point; lane q handles dims [4q,4q+4).
// Per-wave LDS replicas + native f32 LDS atomics (unsafeAtomicAdd -> ds_add_f32).
__global__ void __launch_bounds__(256) k_sums(const float4* __restrict__ feat,
                                              const int* __restrict__ lab,
                                              float* __restrict__ ws) {
    __shared__ float s_sums[4][NCL * 17];
    __shared__ float s_cnt[4][NCL];
    const int tid = threadIdx.x;
    const int wv = tid >> 6;
    for (int i = tid; i < 4 * NCL * 17; i += 256) (&s_sums[0][0])[i] = 0.f;
    for (int i = tid; i < 4 * NCL; i += 256) (&s_cnt[0][0])[i] = 0.f;
    __syncthreads();

    float* __restrict__ mysums = s_sums[wv];
    float* __restrict__ mycnt = s_cnt[wv];

    const int total = NPTS * 4;
    const int stride = gridDim.x * 256;
    for (int idx = blockIdx.x * 256 + tid; idx < total; idx += stride) {
        int p = idx >> 2, q = idx & 3;
        int l = lab[p];
        float4 v = feat[idx];
        float* dst = &mysums[l * 17 + q * 4];
        unsafeAtomicAdd(dst + 0, v.x);
        unsafeAtomicAdd(dst + 1, v.y);
        unsafeAtomicAdd(dst + 2, v.z);
        unsafeAtomicAdd(dst + 3, v.w);
        if (q == 0) unsafeAtomicAdd(&mycnt[l], 1.0f);
    }
    __syncthreads();

    for (int i = tid; i < NCL * DIM; i += 256) {
        int r = i >> 4, c = i & 15;
        float v = s_sums[0][r * 17 + c] + s_sums[1][r * 17 + c] +
                  s_sums[2][r * 17 + c] + s_sums[3][r * 17 + c];
        unsafeAtomicAdd(&ws[WS_SUMS + i], v);
    }
    for (int i = tid; i < NCL; i += 256) {
        float v = s_cnt[0][i] + s_cnt[1][i] + s_cnt[2][i] + s_cnt[3][i];
        unsafeAtomicAdd(&ws[WS_CNT + i], v);
    }
}

// Tiny: means = sums/counts; inter-pair hinge; reg norm. One block, 256 thr.
__global__ void __launch_bounds__(256) k_means_inter(float* __restrict__ ws) {
    __shared__ float s_means[NCL * 17];
    __shared__ float red[8];
    int tid = threadIdx.x;

    for (int i = tid; i < NCL * DIM; i += 256) {
        float m = ws[WS_SUMS + i] / ws[WS_CNT + (i >> 4)];
        ws[WS_MEANS + i] = m;
        s_means[(i >> 4) * 17 + (i & 15)] = m;
    }
    __syncthreads();

    float inter = 0.f;
    for (int pr = tid; pr < NCL * NCL; pr += 256) {
        int i = pr >> 6, j = pr & 63;
        if (i != j) {
            float ss = 0.f;
#pragma unroll
            for (int k = 0; k < DIM; ++k) {
                float dv = s_means[i * 17 + k] - s_means[j * 17 + k] + EPSF;
                ss += dv * dv;
            }
            float h = fmaxf(3.0f - sqrtf(ss), 0.f);  // 2*INTER_MARGIN = 3.0
            inter += h * h;
        }
    }
    float reg = 0.f;
    if (tid < NCL) {
        float ss = 0.f;
#pragma unroll
        for (int k = 0; k < DIM; ++k) {
            float m = s_means[tid * 17 + k] + EPSF;
            ss += m * m;
        }
        reg = sqrtf(ss);
    }
#pragma unroll
    for (int m = 1; m < 64; m <<= 1) {
        inter += __shfl_xor(inter, m);
        reg += __shfl_xor(reg, m);
    }
    int wave = tid >> 6;
    if ((tid & 63) == 0) { red[wave] = inter; red[4 + wave] = reg; }
    __syncthreads();
    if (tid == 0) {
        float it = red[0] + red[1] + red[2] + red[3];
        float rg = red[4] + red[5] + red[6] + red[7];
        ws[WS_INTER] = it / (float)(NCL * (NCL - 1));
        ws[WS_REG] = rg / (float)NCL;
    }
}

// Pass 2: per-cluster sum of hinge^2 of (||x - mean[label] + eps|| - 0.5).
__global__ void __launch_bounds__(256) k_intra(const float4* __restrict__ feat,
                                               const int* __restrict__ lab,
                                               float* __restrict__ ws) {
    __shared__ float s_means[NCL * 17];
    __shared__ float s_h2[4][NCL];
    const int tid = threadIdx.x;
    const int wv = tid >> 6;
    for (int i = tid; i < NCL * DIM; i += 256)
        s_means[(i >> 4) * 17 + (i & 15)] = ws[WS_MEANS + i];
    for (int i = tid; i < 4 * NCL; i += 256) (&s_h2[0][0])[i] = 0.f;
    __syncthreads();

    float* __restrict__ myh2 = s_h2[wv];

    const int total = NPTS * 4;
    const int stride = gridDim.x * 256;
    for (int idx = blockIdx.x * 256 + tid; idx < total; idx += stride) {
        int p = idx >> 2, q = idx & 3;
        int l = lab[p];
        float4 v = feat[idx];
        const float* m = &s_means[l * 17 + q * 4];
        float d0 = v.x - m[0] + EPSF;
        float d1 = v.y - m[1] + EPSF;
        float d2 = v.z - m[2] + EPSF;
        float d3 = v.w - m[3] + EPSF;
        float ss = d0 * d0 + d1 * d1 + d2 * d2 + d3 * d3;
        ss += __shfl_xor(ss, 1);
        ss += __shfl_xor(ss, 2);
        if (q == 0) {
            float h = fmaxf(sqrtf(ss) - 0.5f, 0.f);
            unsafeAtomicAdd(&myh2[l], h * h);
        }
    }
    __syncthreads();
    for (int i = tid; i < NCL; i += 256) {
        float v = s_h2[0][i] + s_h2[1][i] + s_h2[2][i] + s_h2[3][i];
        unsafeAtomicAdd(&ws[WS_H2 + i], v);
    }
}

// Final combine: intra = mean_c(h2sum_c / count_c); loss scalar.
__global__ void k_final(const float* __restrict__ ws, float* __restrict__ out) {
    int t = threadIdx.x;  // 64 threads
    float v = ws[WS_H2 + t] / ws[WS_CNT + t];
#pragma unroll
    for (int m = 1; m < 64; m <<= 1) v += __shfl_xor(v, m);
    if (t == 0) {
        float intra = v / (float)NCL;
        out[0] = intra + ws[WS_INTER] + 0.001f * ws[WS_REG];
    }
}

extern "C" void kernel_launch(void* const* d_in, const int* in_sizes, int n_in,
                              void* d_out, int out_size, void* d_ws, size_t ws_size,
                              hipStream_t stream) {
    const float4* feat = (const float4*)d_in[0];
    const int* lab = (const int*)d_in[1];
    float* ws = (float*)d_ws;
    float* out = (float*)d_out;

    hipMemsetAsync(d_ws, 0, WS_FLOATS * sizeof(float), stream);

    const int blocks = 2048;
    k_sums<<<blocks, 256, 0, stream>>>(feat, lab, ws);
    k_means_inter<<<1, 256, 0, stream>>>(ws);
    k_intra<<<blocks, 256, 0, stream>>>(feat, lab, ws);
    k_final<<<1, 64, 0, stream>>>(ws, out);
}

// Round 3
// 95.433 us; speedup vs baseline: 2.7448x; 2.7448x over previous
//
#include <hip/hip_runtime.h>
#include <hip/hip_bf16.h>
#include <math.h>

#define NPTS 2000000
#define NCL 64
#define EPSF 1e-8f
#define NB_SUMS 1024
#define NB_INTRA 2048

typedef __attribute__((ext_vector_type(8))) short bf16x8;
typedef __attribute__((ext_vector_type(4))) float f32x4;

__device__ __forceinline__ unsigned pk2(float a, float b) {
    __hip_bfloat162 h = __float22bfloat162_rn(make_float2(a, b));
    union { __hip_bfloat162 h; unsigned u; } x;
    x.h = h;
    return x.u;  // low 16 = a, high 16 = b
}
__device__ __forceinline__ unsigned oh2(int a, int b, int c) {
    return (a == c ? 0x3F80u : 0u) | (b == c ? 0x3F800000u : 0u);  // bf16 {1.0,1.0} selects
}

// Pass 1: segment-sum via one-hot MFMA. Each wave: 64 points/iter, staged to LDS
// as bf16 [64pt][16d], read back transposed with ds_read_b64_tr_b16 to form the
// B fragment (k = points, n = dims). A = one-hot(labels) built in registers,
// 4 cluster-groups of 16. Counts via MFMA against all-ones B. No atomics in loop.
__global__ void __launch_bounds__(256) k_sums(const float4* __restrict__ feat,
                                              const int* __restrict__ lab,
                                              float* __restrict__ part, int nPart) {
    __shared__ __align__(16) float smem[4 * 1088];
    const int tid = threadIdx.x;
    const int l = tid & 63, w = tid >> 6, g = l >> 4, mcol = l & 15;

    const unsigned lds0 = (unsigned)(uintptr_t)(&smem[0]);
    const unsigned trb = lds0 + (unsigned)(w * 2048 + l * 8);
    uint2* tw = (uint2*)((unsigned short*)smem + w * 1024);

    f32x4 accS[4], accC[4];
#pragma unroll
    for (int i = 0; i < 4; ++i) {
        accS[i] = (f32x4){0.f, 0.f, 0.f, 0.f};
        accC[i] = (f32x4){0.f, 0.f, 0.f, 0.f};
    }
    bf16x8 ones;
#pragma unroll
    for (int i = 0; i < 8; ++i) ones[i] = (short)0x3F80;

    const int wstride = gridDim.x * 4;
    for (int wc = blockIdx.x * 4 + w; wc * 64 < NPTS; wc += wstride) {
        const int P = wc * 64;
        // coalesced: wave reads 4KB of features + 256B of labels
        float4 f0 = feat[P * 4 + l];
        float4 f1 = feat[P * 4 + 64 + l];
        float4 f2 = feat[P * 4 + 128 + l];
        float4 f3 = feat[P * 4 + 192 + l];
        int4 La0 = *(const int4*)(lab + P + 4 * g);        // points 4g..4g+3   (chunk0 k=8g..8g+3)
        int4 Lb0 = *(const int4*)(lab + P + 16 + 4 * g);   // points 16+4g..    (chunk0 k=8g+4..8g+7)
        int4 La1 = *(const int4*)(lab + P + 32 + 4 * g);
        int4 Lb1 = *(const int4*)(lab + P + 48 + 4 * g);

        // stage bf16 tile [64][16], row-major; ds_write_b64 conflict-free
        tw[l]       = make_uint2(pk2(f0.x, f0.y), pk2(f0.z, f0.w));
        tw[64 + l]  = make_uint2(pk2(f1.x, f1.y), pk2(f1.z, f1.w));
        tw[128 + l] = make_uint2(pk2(f2.x, f2.y), pk2(f2.z, f2.w));
        tw[192 + l] = make_uint2(pk2(f3.x, f3.y), pk2(f3.z, f3.w));

        asm volatile("s_waitcnt lgkmcnt(0)" ::: "memory");
        unsigned long long t00, t01, t10, t11;
        // tr_b16: lane l elem j <- tile[(l&15) + j*16 + (l>>4)*64 + off/2] = feat_bf16[p][d=l&15]
        asm volatile("ds_read_b64_tr_b16 %0, %1 offset:0"    : "=v"(t00) : "v"(trb));
        asm volatile("ds_read_b64_tr_b16 %0, %1 offset:512"  : "=v"(t01) : "v"(trb));
        asm volatile("ds_read_b64_tr_b16 %0, %1 offset:1024" : "=v"(t10) : "v"(trb));
        asm volatile("ds_read_b64_tr_b16 %0, %1 offset:1536" : "=v"(t11) : "v"(trb));
        asm volatile("s_waitcnt lgkmcnt(0)" ::: "memory");
        __builtin_amdgcn_sched_barrier(0);

        union { unsigned u[4]; bf16x8 h; } B0, B1;
        B0.u[0] = (unsigned)t00; B0.u[1] = (unsigned)(t00 >> 32);
        B0.u[2] = (unsigned)t01; B0.u[3] = (unsigned)(t01 >> 32);
        B1.u[0] = (unsigned)t10; B1.u[1] = (unsigned)(t10 >> 32);
        B1.u[2] = (unsigned)t11; B1.u[3] = (unsigned)(t11 >> 32);

#pragma unroll
        for (int gp = 0; gp < 4; ++gp) {
            const int c = mcol + (gp << 4);
            union { unsigned u[4]; bf16x8 h; } A0, A1;
            A0.u[0] = oh2(La0.x, La0.y, c); A0.u[1] = oh2(La0.z, La0.w, c);
            A0.u[2] = oh2(Lb0.x, Lb0.y, c); A0.u[3] = oh2(Lb0.z, Lb0.w, c);
            A1.u[0] = oh2(La1.x, La1.y, c); A1.u[1] = oh2(La1.z, La1.w, c);
            A1.u[2] = oh2(Lb1.x, Lb1.y, c); A1.u[3] = oh2(Lb1.z, Lb1.w, c);
            accS[gp] = __builtin_amdgcn_mfma_f32_16x16x32_bf16(A0.h, B0.h, accS[gp], 0, 0, 0);
            accC[gp] = __builtin_amdgcn_mfma_f32_16x16x32_bf16(A0.h, ones, accC[gp], 0, 0, 0);
            accS[gp] = __builtin_amdgcn_mfma_f32_16x16x32_bf16(A1.h, B1.h, accS[gp], 0, 0, 0);
            accC[gp] = __builtin_amdgcn_mfma_f32_16x16x32_bf16(A1.h, ones, accC[gp], 0, 0, 0);
        }
    }

    // flush: D layout col=lane&15, row=(lane>>4)*4+reg (guide §3, m89-verified)
    __syncthreads();
    float* fl = smem + w * 1088;
#pragma unroll
    for (int gp = 0; gp < 4; ++gp) {
#pragma unroll
        for (int r = 0; r < 4; ++r) {
            int c = (gp << 4) + ((l >> 4) << 2) + r;
            fl[c * 16 + mcol] = accS[gp][r];
            if (mcol == 0) fl[1024 + c] = accC[gp][r];
        }
    }
    __syncthreads();
    float* dst = part + (unsigned)(blockIdx.x % nPart) * 1088;
    int j0 = tid * 4;
#pragma unroll
    for (int e = 0; e < 4; ++e) {
        float s = smem[j0 + e] + smem[1088 + j0 + e] + smem[2176 + j0 + e] + smem[3264 + j0 + e];
        unsafeAtomicAdd(&dst[j0 + e], s);
    }
    if (tid < 64) {
        float cs = smem[1024 + tid] + smem[1088 + 1024 + tid] +
                   smem[2176 + 1024 + tid] + smem[3264 + 1024 + tid];
        unsafeAtomicAdd(&dst[1024 + tid], cs);
    }
}

// Tree-reduce partials[nPart][1088] -> fs[1088] (sums 0..1023, counts 1024..1087)
__global__ void __launch_bounds__(256) k_reduce(const float* __restrict__ part,
                                                float* __restrict__ fs, int nPart) {
    __shared__ float red[16][17];
    const int t = threadIdx.x, jl = t & 15, seg = t >> 4;
    const int j = blockIdx.x * 16 + jl;
    float a = 0.f;
    for (int p = seg; p < nPart; p += 16) a += part[p * 1088 + j];
    red[seg][jl] = a;
    __syncthreads();
    if (t < 16) {
        float s = 0.f;
#pragma unroll
        for (int k = 0; k < 16; ++k) s += red[k][t];
        fs[blockIdx.x * 16 + t] = s;
    }
}

// means, inv-counts, inter-pair hinge, reg norm. One block.
__global__ void __launch_bounds__(256) k_means_inter(const float* __restrict__ fs,
                                                     float* __restrict__ means,
                                                     float* __restrict__ icnt,
                                                     float* __restrict__ scal) {
    __shared__ float s_means[NCL * 17];
    __shared__ float red[8];
    int tid = threadIdx.x;
    for (int i = tid; i < NCL * 16; i += 256) {
        float m = fs[i] / fs[1024 + (i >> 4)];
        means[i] = m;
        s_means[(i >> 4) * 17 + (i & 15)] = m;
    }
    if (tid < NCL) icnt[tid] = 1.0f / fs[1024 + tid];
    __syncthreads();

    float inter = 0.f;
    for (int pr = tid; pr < NCL * NCL; pr += 256) {
        int i = pr >> 6, j = pr & 63;
        if (i != j) {
            float ss = 0.f;
#pragma unroll
            for (int k = 0; k < 16; ++k) {
                float dv = s_means[i * 17 + k] - s_means[j * 17 + k] + EPSF;
                ss += dv * dv;
            }
            float h = fmaxf(3.0f - sqrtf(ss), 0.f);  // 2*INTER_MARGIN = 3.0
            inter += h * h;
        }
    }
    float reg = 0.f;
    if (tid < NCL) {
        float ss = 0.f;
#pragma unroll
        for (int k = 0; k < 16; ++k) {
            float m = s_means[tid * 17 + k] + EPSF;
            ss += m * m;
        }
        reg = sqrtf(ss);
    }
#pragma unroll
    for (int m = 1; m < 64; m <<= 1) {
        inter += __shfl_xor(inter, m);
        reg += __shfl_xor(reg, m);
    }
    int wave = tid >> 6;
    if ((tid & 63) == 0) { red[wave] = inter; red[4 + wave] = reg; }
    __syncthreads();
    if (tid == 0) {
        float it = red[0] + red[1] + red[2] + red[3];
        float rg = red[4] + red[5] + red[6] + red[7];
        scal[0] = it / (float)(NCL * (NCL - 1));
        scal[1] = rg / (float)NCL;
    }
}

// Pass 2: acc += h^2 * inv_cnt[label] in REGISTERS (intra = sum/C). No atomics.
__global__ void __launch_bounds__(256) k_intra(const float4* __restrict__ feat,
                                               const int* __restrict__ lab,
                                               const float* __restrict__ means,
                                               const float* __restrict__ icnt,
                                               float* __restrict__ pintra) {
    __shared__ float s_m[NCL * 17];
    const int tid = threadIdx.x;
    for (int i = tid; i < NCL * 16; i += 256) s_m[(i >> 4) * 17 + (i & 15)] = means[i];
    for (int i = tid; i < NCL; i += 256) s_m[i * 17 + 16] = icnt[i];
    __syncthreads();

    float acc = 0.f;
    const int total = NPTS * 4;
    const int stride = gridDim.x * 256;
    for (int idx = blockIdx.x * 256 + tid; idx < total; idx += stride) {
        int p = idx >> 2, q = idx & 3;
        int lb = lab[p];
        float4 v = feat[idx];
        const float* m = &s_m[lb * 17 + q * 4];
        float d0 = v.x - m[0] + EPSF;
        float d1 = v.y - m[1] + EPSF;
        float d2 = v.z - m[2] + EPSF;
        float d3 = v.w - m[3] + EPSF;
        float ss = d0 * d0 + d1 * d1 + d2 * d2 + d3 * d3;
        ss += __shfl_xor(ss, 1);
        ss += __shfl_xor(ss, 2);
        if (q == 0) {
            float h = fmaxf(sqrtf(ss) - 0.5f, 0.f);
            acc += h * h * s_m[lb * 17 + 16];
        }
    }
#pragma unroll
    for (int mm = 1; mm < 64; mm <<= 1) acc += __shfl_xor(acc, mm);
    __shared__ float r4[4];
    if ((tid & 63) == 0) r4[tid >> 6] = acc;
    __syncthreads();
    if (tid == 0) pintra[blockIdx.x] = r4[0] + r4[1] + r4[2] + r4[3];
}

__global__ void k_final(const float* __restrict__ pintra, const float* __restrict__ scal,
                        float* __restrict__ out) {
    int t = threadIdx.x;  // 256
    float v = 0.f;
#pragma unroll
    for (int i = 0; i < NB_INTRA / 256; ++i) v += pintra[t + i * 256];
#pragma unroll
    for (int mm = 1; mm < 64; mm <<= 1) v += __shfl_xor(v, mm);
    __shared__ float r4[4];
    if ((t & 63) == 0) r4[t >> 6] = v;
    __syncthreads();
    if (t == 0) out[0] = (r4[0] + r4[1] + r4[2] + r4[3]) / (float)NCL + scal[0] + 0.001f * scal[1];
}

extern "C" void kernel_launch(void* const* d_in, const int* in_sizes, int n_in,
                              void* d_out, int out_size, void* d_ws, size_t ws_size,
                              hipStream_t stream) {
    const float4* feat = (const float4*)d_in[0];
    const int* lab = (const int*)d_in[1];
    float* ws = (float*)d_ws;
    float* out = (float*)d_out;

    // ws layout: part[nPart][1088] | fs[1088] | means[1024] | icnt[64] | scal[2] | pintra[2048]
    size_t wsf = ws_size / 4;
    long avail = (long)wsf - 4226;
    int nPart = (int)(avail / 1088);
    if (nPart < 1) nPart = 1;
    if (nPart > NB_SUMS) nPart = NB_SUMS;

    float* part = ws;
    float* fs = part + (size_t)nPart * 1088;
    float* means = fs + 1088;
    float* icnt = means + 1024;
    float* scal = icnt + 64;
    float* pintra = scal + 2;

    hipMemsetAsync(d_ws, 0, ((size_t)nPart * 1088 + 4226) * sizeof(float), stream);

    k_sums<<<NB_SUMS, 256, 0, stream>>>(feat, lab, part, nPart);
    k_reduce<<<68, 256, 0, stream>>>(part, fs, nPart);
    k_means_inter<<<1, 256, 0, stream>>>(fs, means, icnt, scal);
    k_intra<<<NB_INTRA, 256, 0, stream>>>(feat, lab, means, icnt, pintra);
    k_final<<<1, 256, 0, stream>>>(pintra, scal, out);
}